// Round 9
// baseline (232.981 us; speedup 1.0000x reference)
//
#include <hip/hip_runtime.h>
#include <hip/hip_bf16.h>

typedef __bf16 bf16;
typedef __bf16 bf16x8 __attribute__((ext_vector_type(8)));
typedef float f32x4 __attribute__((ext_vector_type(4)));

#define N_B 4
#define T_S 2048
#define D_M 1024
#define H_N 16
#define D_K 64
#define D3 3072
#define NEG_BIG (-1e30f)
#define QSCALE 0.18033688011112042f  /* 0.125 * log2(e) */

#if __has_builtin(__builtin_amdgcn_exp2f)
#define EXP2(x) __builtin_amdgcn_exp2f(x)
#else
#define EXP2(x) exp2f(x)
#endif

__device__ __forceinline__ void gload_lds16(const bf16* g, bf16* l) {
    __builtin_amdgcn_global_load_lds((const __attribute__((address_space(1))) void*)g,
                                     (__attribute__((address_space(3))) void*)l, 16, 0, 0);
}

// Probe: true => data is fp32 (see r0 notes).
__device__ __forceinline__ bool probe_fp32(const void* p) {
    const unsigned int* w = (const unsigned int*)p;
    int weird = 0;
#pragma unroll
    for (int i = 0; i < 16; ++i) {
        unsigned int v = w[i];
        unsigned int e = (v >> 7) & 0xFFu;
        if ((v & 0xFFFFu) != 0u && (e < 100u || e > 140u)) weird++;
    }
    return weird >= 4;
}

// ---------------- fused prologue: convert z + transpose both weights ----------------
__global__ __launch_bounds__(256) void prep(const void* __restrict__ z, bf16* __restrict__ zb,
                                            const void* __restrict__ Wqkv, bf16* __restrict__ WqkvT,
                                            const void* __restrict__ Wout, bf16* __restrict__ WoutT) {
    __shared__ bf16 tile[32][33];
    const int b = blockIdx.x;
    const int t = threadIdx.x;

    if (b < 4096) {
        const int i = (b * 256 + t) * 8;
        if (probe_fp32(z)) {
            const float* zf = (const float*)z;
            float4 u0 = *(const float4*)(zf + i);
            float4 u1 = *(const float4*)(zf + i + 4);
            union { uint4 q; bf16 h[8]; } pk;
            pk.h[0] = (bf16)u0.x; pk.h[1] = (bf16)u0.y;
            pk.h[2] = (bf16)u0.z; pk.h[3] = (bf16)u0.w;
            pk.h[4] = (bf16)u1.x; pk.h[5] = (bf16)u1.y;
            pk.h[6] = (bf16)u1.z; pk.h[7] = (bf16)u1.w;
            *(uint4*)(zb + i) = pk.q;
        } else {
            *(uint4*)(zb + i) = ((const uint4*)z)[b * 256 + t];
        }
        return;
    }

    const void* in; bf16* out; int R, C, c0, r0;
    if (b < 7168) {
        int idx = b - 4096;
        in = Wqkv; out = WqkvT; R = 1024; C = 3072;
        c0 = (idx % 96) * 32; r0 = (idx / 96) * 32;
    } else {
        int idx = b - 7168;
        in = Wout; out = WoutT; R = 1024; C = 1024;
        c0 = (idx & 31) * 32; r0 = (idx >> 5) * 32;
    }
    const int tx = t & 31, ty = t >> 5;
    if (probe_fp32(in)) {
        const float* inf_ = (const float*)in;
        for (int i = 0; i < 4; ++i)
            tile[ty + i * 8][tx] = (bf16)inf_[(size_t)(r0 + ty + i * 8) * C + c0 + tx];
    } else {
        const bf16* inb = (const bf16*)in;
        for (int i = 0; i < 4; ++i)
            tile[ty + i * 8][tx] = inb[(size_t)(r0 + ty + i * 8) * C + c0 + tx];
    }
    __syncthreads();
    for (int i = 0; i < 4; ++i)
        out[(size_t)(c0 + ty + i * 8) * R + r0 + tx] = tile[tx][ty + i * 8];
}

// ---------------- GEMM: C = A[M][K] @ Bt[N][K]^T (bf16 in, fp32 acc) ----------------
// r3-exact (best measured: G1 = 69.3-69.9 us across 4 rounds). 256x128 tile,
// BK=64, 8 waves 4Mx2N, m201-style phase pair per K-tile, 3-slot LDS ring,
// counted vmcnt(6). modeC 1: fp32 out stride N. modeC 2: QKV split epilogue.
__global__ __launch_bounds__(512, 2) void gemm256(const bf16* __restrict__ A,
                                                  const bf16* __restrict__ Bt,
                                                  void* __restrict__ C,
                                                  bf16* __restrict__ Kf,
                                                  bf16* __restrict__ Vf,
                                                  int M, int N, int K,
                                                  int modeC) {
    __shared__ bf16 As[3][256 * 64];   // 3 x 32 KB
    __shared__ bf16 Bs[3][128 * 64];   // 3 x 16 KB
    const int t = threadIdx.x;
    const int m0 = blockIdx.y * 256, n0 = blockIdx.x * 128;
    const int w = t >> 6, lane = t & 63, quad = lane >> 4, l15 = lane & 15;
    const int wr = (w >> 1) * 64, wc = (w & 1) * 64;
    const int sr = t >> 3;                     // staging row within a 64-row issue
    const int sg = ((t & 7) ^ (sr & 7)) * 8;   // pre-swizzled k-segment (elements)
    const int xorL = (l15 & 7) * 8;

    // per-thread global staging bases (advance by 64 per staged tile)
    const bf16* a0 = A + (size_t)(m0 + sr) * K + sg;
    const bf16* a1 = A + (size_t)(m0 + 64 + sr) * K + sg;
    const bf16* a2 = A + (size_t)(m0 + 128 + sr) * K + sg;
    const bf16* a3 = A + (size_t)(m0 + 192 + sr) * K + sg;
    const bf16* b0 = Bt + (size_t)(n0 + sr) * K + sg;
    const bf16* b1 = Bt + (size_t)(n0 + 64 + sr) * K + sg;
    const int ldsOff = w * 512;   // wave-uniform LDS landing offset

    f32x4 acc[4][4];
    const f32x4 zero4 = {0.f, 0.f, 0.f, 0.f};
#pragma unroll
    for (int i = 0; i < 4; ++i)
#pragma unroll
        for (int j = 0; j < 4; ++j) acc[i][j] = zero4;

    const int nt = K >> 6;

    // prologue: stage tiles 0 and 1 (6 gloads each: A x4, B x2)
    gload_lds16(a0, &As[0][0 * 4096 + ldsOff]);
    gload_lds16(a1, &As[0][1 * 4096 + ldsOff]);
    gload_lds16(a2, &As[0][2 * 4096 + ldsOff]);
    gload_lds16(a3, &As[0][3 * 4096 + ldsOff]);
    gload_lds16(b0, &Bs[0][0 * 4096 + ldsOff]);
    gload_lds16(b1, &Bs[0][1 * 4096 + ldsOff]);
    if (nt > 1) {
        gload_lds16(a0 + 64, &As[1][0 * 4096 + ldsOff]);
        gload_lds16(a1 + 64, &As[1][1 * 4096 + ldsOff]);
        gload_lds16(a2 + 64, &As[1][2 * 4096 + ldsOff]);
        gload_lds16(a3 + 64, &As[1][3 * 4096 + ldsOff]);
        gload_lds16(b0 + 64, &Bs[1][0 * 4096 + ldsOff]);
        gload_lds16(b1 + 64, &Bs[1][1 * 4096 + ldsOff]);
        asm volatile("s_waitcnt vmcnt(6)" ::: "memory");
    } else {
        asm volatile("s_waitcnt vmcnt(0)" ::: "memory");
    }
    __builtin_amdgcn_sched_barrier(0);
    __builtin_amdgcn_s_barrier();
    __builtin_amdgcn_sched_barrier(0);

    int cur = 0;
    for (int tt = 0; tt < nt; ++tt) {
        const bf16* Ac = As[cur];
        const bf16* Bc = Bs[cur];
        int pf = cur + 2; if (pf >= 3) pf -= 3;      // ring slot for tile tt+2
        const bool do_pf = (tt + 2 < nt);
        const int kpf = (tt + 2) << 6;

        // ================= phase 0 (kk = 0) =================
        {
            const int colOff = (quad * 8) ^ xorL;
            bf16x8 af[4], bfv[4];
#pragma unroll
            for (int i = 0; i < 4; ++i)
                af[i] = *(const bf16x8*)(Ac + (wr + i * 16 + l15) * 64 + colOff);
#pragma unroll
            for (int j = 0; j < 4; ++j)
                bfv[j] = *(const bf16x8*)(Bc + (wc + j * 16 + l15) * 64 + colOff);
            if (do_pf) {
                gload_lds16(a0 + kpf, &As[pf][0 * 4096 + ldsOff]);
                gload_lds16(a1 + kpf, &As[pf][1 * 4096 + ldsOff]);
                gload_lds16(a2 + kpf, &As[pf][2 * 4096 + ldsOff]);
            }
            __builtin_amdgcn_sched_barrier(0);
            __builtin_amdgcn_s_barrier();
            asm volatile("s_waitcnt lgkmcnt(0)" ::: "memory");
            __builtin_amdgcn_sched_barrier(0);
            __builtin_amdgcn_s_setprio(1);
#pragma unroll
            for (int i = 0; i < 4; ++i)
#pragma unroll
                for (int j = 0; j < 4; ++j)
                    acc[i][j] = __builtin_amdgcn_mfma_f32_16x16x32_bf16(af[i], bfv[j], acc[i][j], 0, 0, 0);
            __builtin_amdgcn_s_setprio(0);
            __builtin_amdgcn_sched_barrier(0);
            __builtin_amdgcn_s_barrier();
            __builtin_amdgcn_sched_barrier(0);
        }

        // ================= phase 1 (kk = 1) =================
        {
            const int colOff = (32 + quad * 8) ^ xorL;
            bf16x8 af[4], bfv[4];
#pragma unroll
            for (int i = 0; i < 4; ++i)
                af[i] = *(const bf16x8*)(Ac + (wr + i * 16 + l15) * 64 + colOff);
#pragma unroll
            for (int j = 0; j < 4; ++j)
                bfv[j] = *(const bf16x8*)(Bc + (wc + j * 16 + l15) * 64 + colOff);
            if (do_pf) {
                gload_lds16(a3 + kpf, &As[pf][3 * 4096 + ldsOff]);
                gload_lds16(b0 + kpf, &Bs[pf][0 * 4096 + ldsOff]);
                gload_lds16(b1 + kpf, &Bs[pf][1 * 4096 + ldsOff]);
                asm volatile("s_waitcnt vmcnt(6)" ::: "memory");   // tile tt+1 retired, tt+2 in flight
            } else {
                asm volatile("s_waitcnt vmcnt(0)" ::: "memory");   // tail: drain
            }
            __builtin_amdgcn_sched_barrier(0);
            __builtin_amdgcn_s_barrier();
            asm volatile("s_waitcnt lgkmcnt(0)" ::: "memory");
            __builtin_amdgcn_sched_barrier(0);
            __builtin_amdgcn_s_setprio(1);
#pragma unroll
            for (int i = 0; i < 4; ++i)
#pragma unroll
                for (int j = 0; j < 4; ++j)
                    acc[i][j] = __builtin_amdgcn_mfma_f32_16x16x32_bf16(af[i], bfv[j], acc[i][j], 0, 0, 0);
            __builtin_amdgcn_s_setprio(0);
            __builtin_amdgcn_sched_barrier(0);
            __builtin_amdgcn_s_barrier();
            __builtin_amdgcn_sched_barrier(0);
        }
        cur = cur + 1; if (cur == 3) cur = 0;
    }

    // epilogue — C/D layout: row = quad*4 + reg, col = l15 (m89/m91 verified)
    if (modeC == 1) {
        float* Cf = (float*)C;
        for (int i = 0; i < 4; ++i)
            for (int fc = 0; fc < 4; ++fc)
                for (int r = 0; r < 4; ++r)
                    Cf[(size_t)(m0 + wr + i * 16 + quad * 4 + r) * N
                       + (n0 + wc + fc * 16 + l15)] = acc[i][fc][r];
    } else if (n0 < 1024) {
        bf16* q = (bf16*)C;
        for (int i = 0; i < 4; ++i)
            for (int fc = 0; fc < 4; ++fc)
                for (int r = 0; r < 4; ++r)
                    q[(size_t)(m0 + wr + i * 16 + quad * 4 + r) * 1024
                      + (n0 + wc + fc * 16 + l15)] = (bf16)(acc[i][fc][r] * QSCALE);
    } else if (n0 < 2048) {
        // K region -> Kf fragment layout
        for (int i = 0; i < 4; ++i) {
            int rowb = m0 + wr + i * 16 + quad * 4;
            int nb = rowb >> 11, tt = rowb & 2047;
            int kt = tt >> 6, f = (tt >> 4) & 3, l15k = tt & 15;
            for (int fc = 0; fc < 4; ++fc) {
                int col = n0 + wc + fc * 16 + l15 - 1024;
                int h = col >> 6, dk = col & 63;
                int ks = dk >> 5, qdk = (dk >> 3) & 3, j = dk & 7;
                size_t base = ((size_t)((nb * 16 + h) * 32 + kt) * 8 + ks * 4 + f) * 512 + j;
                for (int r = 0; r < 4; ++r)
                    Kf[base + (qdk * 16 + l15k + r) * 8] = (bf16)acc[i][fc][r];
            }
        }
    } else {
        // V region -> Vf fragment layout (packed ushort4)
        for (int i = 0; i < 4; ++i) {
            int rowb = m0 + wr + i * 16 + quad * 4;
            int nb = rowb >> 11, tt = rowb & 2047;
            int kt = tt >> 6, ks = (tt >> 5) & 1, qdv = (tt >> 3) & 3, j0 = tt & 7;
            for (int fc = 0; fc < 4; ++fc) {
                int col = n0 + wc + fc * 16 + l15 - 2048;
                int h = col >> 6, dl = col & 63;
                int fv = dl >> 4, l15v = dl & 15;
                union { ushort4 u; bf16 hh[4]; } pk;
                for (int r = 0; r < 4; ++r) pk.hh[r] = (bf16)acc[i][fc][r];
                *(ushort4*)(Vf + ((size_t)((nb * 16 + h) * 32 + kt) * 8 + ks * 4 + fv) * 512
                            + (qdv * 16 + l15v) * 8 + j0) = pk.u;
            }
        }
    }
}

// ---------------- fused causal attention, S^T form, no online max ----------------
// r9: block = (head, 256-row q-tile), 8 waves (512 thr) in lockstep over a
// shared kt range. Halves global K/V staging vs r8 (147 MB vs 278 MB): each
// head's K/V now staged by 8 blocks instead of 16. Grid = 512 blocks with
// BALANCED pairing: tiles/block = 4*qt+4, perm {7,6,5,4,0,1,2,3} makes every
// CU's two blocks sum to exactly 36 tiles. Staging: 512 thr x 16B = 8 KB = one
// full K (or V) tile per issue-line; double-buffered; __syncthreads drains
// vmcnt -> published. Per-wave math/frag offsets identical to r8 => bitwise-
// identical output. LDS 68 KB -> 2 blocks/CU possible.
#define LDP 72
__global__ __launch_bounds__(512, 2) void attn_fused(const bf16* __restrict__ q,
                                                     const bf16* __restrict__ Kf,
                                                     const bf16* __restrict__ Vf,
                                                     bf16* __restrict__ attn_out) {
    __shared__ bf16 Ks[2][4096];        // 2 x 8 KB K tile (fragment layout)
    __shared__ bf16 Vs[2][4096];        // 2 x 8 KB V tile
    __shared__ bf16 Pl[8 * 32 * LDP];   // per-wave private 32x64 P strip (36 KB)

    const int b = blockIdx.x;
    const int head = b & 63;
    const int g = b >> 6;               // 0..7
    // balanced pairing: CU pairs (7,0),(6,1),(5,2),(4,3) -> 36 tiles each
    const int permv = (g < 4) ? (7 - g) : (g - 4);
    const int qt = permv;               // 256-row q-tile index, 0..7
    const int n = head >> 4, h = head & 15;
    const int t = threadIdx.x;
    const int w = t >> 6, lane = t & 63, qd = lane >> 4, l15 = lane & 15;
    const int q0w = qt * 256 + w * 32;  // this wave's 32 q-rows
    const size_t rowBase = (size_t)n * T_S;
    const bf16* KfH = Kf + (size_t)head * 32 * 4096;
    const bf16* VfH = Vf + (size_t)head * 32 * 4096;
    bf16* Plw = Pl + w * 32 * LDP;

    // persistent Q b-frags (pre-scaled by QSCALE): [qh][ks]
    bf16x8 bQ[2][2];
#pragma unroll
    for (int qh = 0; qh < 2; ++qh)
#pragma unroll
        for (int ks = 0; ks < 2; ++ks)
            bQ[qh][ks] = *(const bf16x8*)(q + (rowBase + q0w + qh * 16 + l15) * 1024
                                          + h * 64 + ks * 32 + qd * 8);

    float l_lane[2] = {0.f, 0.f};
    f32x4 oacc[2][4];
    const f32x4 zero4 = {0.f, 0.f, 0.f, 0.f};
#pragma unroll
    for (int qh = 0; qh < 2; ++qh)
#pragma unroll
        for (int fd = 0; fd < 4; ++fd) oacc[qh][fd] = zero4;

    const int ktmax_w = (q0w + 31) >> 6;   // this wave's causal compute limit
    const int ktmax_b = 4 * qt + 3;        // block stage limit

    // stage tile 0 into buffer 0: one 8 KB line each for K and V
    // (wave w covers chunk w: dst wave-uniform, src per-lane)
    gload_lds16(KfH + w * 512 + lane * 8, &Ks[0][w * 512]);
    gload_lds16(VfH + w * 512 + lane * 8, &Vs[0][w * 512]);
    __syncthreads();   // drains vmcnt -> tile 0 published

    int cur = 0;
    for (int kt = 0; kt <= ktmax_b; ++kt) {
        // prefetch tile kt+1 into the other buffer (drained by end-of-iter barrier)
        if (kt + 1 <= ktmax_b) {
            const bf16* Kn = KfH + (size_t)(kt + 1) * 4096;
            const bf16* Vn = VfH + (size_t)(kt + 1) * 4096;
            gload_lds16(Kn + w * 512 + lane * 8, &Ks[cur ^ 1][w * 512]);
            gload_lds16(Vn + w * 512 + lane * 8, &Vs[cur ^ 1][w * 512]);
        }

        if (kt <= ktmax_w) {   // wave-uniform: tiles beyond are fully masked
            const int k0r = kt * 64;

            // K frags from LDS (identical values/offsets as r8)
            bf16x8 aK[2][4];
#pragma unroll
            for (int fr = 0; fr < 8; ++fr)
                aK[fr >> 2][fr & 3] = *(const bf16x8*)(&Ks[cur][fr * 512 + lane * 8]);

            // S^T[kv][q] = K @ Q^T
            f32x4 sacc[2][4];
#pragma unroll
            for (int qh = 0; qh < 2; ++qh)
#pragma unroll
                for (int fc = 0; fc < 4; ++fc) sacc[qh][fc] = zero4;
#pragma unroll
            for (int ks = 0; ks < 2; ++ks)
#pragma unroll
                for (int fc = 0; fc < 4; ++fc) {
                    sacc[0][fc] = __builtin_amdgcn_mfma_f32_16x16x32_bf16(aK[ks][fc], bQ[0][ks], sacc[0][fc], 0, 0, 0);
                    sacc[1][fc] = __builtin_amdgcn_mfma_f32_16x16x32_bf16(aK[ks][fc], bQ[1][ks], sacc[1][fc], 0, 0, 0);
                }

            // causal mask (diagonal tiles only)
            if (k0r + 63 > q0w) {
#pragma unroll
                for (int qh = 0; qh < 2; ++qh) {
                    const int qq = q0w + qh * 16 + l15;
#pragma unroll
                    for (int fc = 0; fc < 4; ++fc)
#pragma unroll
                        for (int rr = 0; rr < 4; ++rr)
                            if (k0r + fc * 16 + qd * 4 + rr > qq) sacc[qh][fc][rr] = NEG_BIG;
                }
            }

            // P = exp2(S) — native v_exp_f32; per-lane l accumulation
#pragma unroll
            for (int qh = 0; qh < 2; ++qh) {
                float rs = 0.f;
#pragma unroll
                for (int fc = 0; fc < 4; ++fc) {
                    union { ushort4 u; bf16 hh[4]; } pk;
#pragma unroll
                    for (int rr = 0; rr < 4; ++rr) {
                        float p = EXP2(sacc[qh][fc][rr]);
                        rs += p;
                        pk.hh[rr] = (bf16)p;
                    }
                    *(ushort4*)(Plw + (qh * 16 + l15) * LDP + fc * 16 + qd * 4) = pk.u;
                }
                l_lane[qh] += rs;
            }

            // V frags from LDS, then O^T += Vt @ P^T
            bf16x8 aV[2][4];
#pragma unroll
            for (int fr = 0; fr < 8; ++fr)
                aV[fr >> 2][fr & 3] = *(const bf16x8*)(&Vs[cur][fr * 512 + lane * 8]);
#pragma unroll
            for (int ks = 0; ks < 2; ++ks) {
                bf16x8 bP0 = *(const bf16x8*)(Plw + l15 * LDP + ks * 32 + qd * 8);
                bf16x8 bP1 = *(const bf16x8*)(Plw + (16 + l15) * LDP + ks * 32 + qd * 8);
#pragma unroll
                for (int fd = 0; fd < 4; ++fd) {
                    oacc[0][fd] = __builtin_amdgcn_mfma_f32_16x16x32_bf16(aV[ks][fd], bP0, oacc[0][fd], 0, 0, 0);
                    oacc[1][fd] = __builtin_amdgcn_mfma_f32_16x16x32_bf16(aV[ks][fd], bP1, oacc[1][fd], 0, 0, 0);
                }
            }
        }

        __syncthreads();   // drains staging vmcnt + all waves' LDS reads of buf cur
        cur ^= 1;
    }

    // epilogue: reduce l across the 4 kv-quads, scale, store
#pragma unroll
    for (int qh = 0; qh < 2; ++qh) {
        float l = l_lane[qh];
        l += __shfl_xor(l, 16, 64);
        l += __shfl_xor(l, 32, 64);
        float inv = 1.f / l;
#pragma unroll
        for (int fd = 0; fd < 4; ++fd) {
            union { ushort4 u; bf16 hh[4]; } pk;
#pragma unroll
            for (int rr = 0; rr < 4; ++rr) pk.hh[rr] = (bf16)(oacc[qh][fd][rr] * inv);
            *(ushort4*)(attn_out + (rowBase + q0w + qh * 16 + l15) * D_M
                        + h * D_K + fd * 16 + qd * 4) = pk.u;
        }
    }
}

extern "C" void kernel_launch(void* const* d_in, const int* in_sizes, int n_in,
                              void* d_out, int out_size, void* d_ws, size_t ws_size,
                              hipStream_t stream) {
    const void* z    = d_in[0];   // [4,2048,1024]  fp32 (or bf16)
    const void* Wqkv = d_in[1];   // [1024,3072]
    const void* Wout = d_in[2];   // [1024,1024]

    char* ws = (char*)d_ws;
    bf16* q     = (bf16*)(ws + 256);                           // 16,777,216 B  [8192][1024]
    bf16* attn  = (bf16*)(ws + 256 + 16777216);                // 16,777,216 B
    bf16* zb    = attn;  // aliased: zb dead before attn is written
    bf16* WqkvT = (bf16*)(ws + 256 + 2 * 16777216);            //  6,291,456 B
    bf16* WoutT = (bf16*)(ws + 256 + 2 * 16777216 + 6291456);  //  2,097,152 B

    // Kf/Vf fragment-packed K/V live in d_out (33,554,432 B exact fit) —
    // written by GEMM1's epilogue, read by attn, then fully overwritten by GEMM2.
    bf16* Kf = (bf16*)d_out;
    bf16* Vf = Kf + 8388608;

    // fused prologue: z->bf16 + both weight transposes (per-block dtype probe)
    prep<<<dim3(8192), 256, 0, stream>>>(z, zb, Wqkv, WqkvT, Wout, WoutT);

    // qkv = zb @ Wqkv : q(*QSCALE) -> q, k -> Kf frags, v -> Vf frags
    gemm256<<<dim3(D3 / 128, (N_B * T_S) / 256), 512, 0, stream>>>(
        zb, WqkvT, q, Kf, Vf, N_B * T_S, D3, D_M, 2);

    // attention: 64 heads x 8 q-tiles of 256 rows, balanced pairing
    attn_fused<<<dim3(64 * 8), 512, 0, stream>>>(q, Kf, Vf, attn);

    // out = attn @ Wout : [8192 x 1024] fp32 out (overwrites Kf/Vf scratch)
    gemm256<<<dim3(D_M / 128, (N_B * T_S) / 256), 512, 0, stream>>>(
        attn, WoutT, d_out, Kf, Vf, N_B * T_S, D_M, D_M, 1);
}

// Round 10
// 232.957 us; speedup vs baseline: 1.0001x; 1.0001x over previous
//
#include <hip/hip_runtime.h>
#include <hip/hip_bf16.h>

typedef __bf16 bf16;
typedef __bf16 bf16x8 __attribute__((ext_vector_type(8)));
typedef float f32x4 __attribute__((ext_vector_type(4)));

#define N_B 4
#define T_S 2048
#define D_M 1024
#define H_N 16
#define D_K 64
#define D3 3072
#define NEG_BIG (-1e30f)
#define QSCALE 0.18033688011112042f  /* 0.125 * log2(e) */

#if __has_builtin(__builtin_amdgcn_exp2f)
#define EXP2(x) __builtin_amdgcn_exp2f(x)
#else
#define EXP2(x) exp2f(x)
#endif

__device__ __forceinline__ void gload_lds16(const bf16* g, bf16* l) {
    __builtin_amdgcn_global_load_lds((const __attribute__((address_space(1))) void*)g,
                                     (__attribute__((address_space(3))) void*)l, 16, 0, 0);
}

// Probe: true => data is fp32 (see r0 notes).
__device__ __forceinline__ bool probe_fp32(const void* p) {
    const unsigned int* w = (const unsigned int*)p;
    int weird = 0;
#pragma unroll
    for (int i = 0; i < 16; ++i) {
        unsigned int v = w[i];
        unsigned int e = (v >> 7) & 0xFFu;
        if ((v & 0xFFFFu) != 0u && (e < 100u || e > 140u)) weird++;
    }
    return weird >= 4;
}

// ---------------- fused prologue: convert z + transpose both weights ----------------
__global__ __launch_bounds__(256) void prep(const void* __restrict__ z, bf16* __restrict__ zb,
                                            const void* __restrict__ Wqkv, bf16* __restrict__ WqkvT,
                                            const void* __restrict__ Wout, bf16* __restrict__ WoutT) {
    __shared__ bf16 tile[32][33];
    const int b = blockIdx.x;
    const int t = threadIdx.x;

    if (b < 4096) {
        const int i = (b * 256 + t) * 8;
        if (probe_fp32(z)) {
            const float* zf = (const float*)z;
            float4 u0 = *(const float4*)(zf + i);
            float4 u1 = *(const float4*)(zf + i + 4);
            union { uint4 q; bf16 h[8]; } pk;
            pk.h[0] = (bf16)u0.x; pk.h[1] = (bf16)u0.y;
            pk.h[2] = (bf16)u0.z; pk.h[3] = (bf16)u0.w;
            pk.h[4] = (bf16)u1.x; pk.h[5] = (bf16)u1.y;
            pk.h[6] = (bf16)u1.z; pk.h[7] = (bf16)u1.w;
            *(uint4*)(zb + i) = pk.q;
        } else {
            *(uint4*)(zb + i) = ((const uint4*)z)[b * 256 + t];
        }
        return;
    }

    const void* in; bf16* out; int R, C, c0, r0;
    if (b < 7168) {
        int idx = b - 4096;
        in = Wqkv; out = WqkvT; R = 1024; C = 3072;
        c0 = (idx % 96) * 32; r0 = (idx / 96) * 32;
    } else {
        int idx = b - 7168;
        in = Wout; out = WoutT; R = 1024; C = 1024;
        c0 = (idx & 31) * 32; r0 = (idx >> 5) * 32;
    }
    const int tx = t & 31, ty = t >> 5;
    if (probe_fp32(in)) {
        const float* inf_ = (const float*)in;
        for (int i = 0; i < 4; ++i)
            tile[ty + i * 8][tx] = (bf16)inf_[(size_t)(r0 + ty + i * 8) * C + c0 + tx];
    } else {
        const bf16* inb = (const bf16*)in;
        for (int i = 0; i < 4; ++i)
            tile[ty + i * 8][tx] = inb[(size_t)(r0 + ty + i * 8) * C + c0 + tx];
    }
    __syncthreads();
    for (int i = 0; i < 4; ++i)
        out[(size_t)(c0 + ty + i * 8) * R + r0 + tx] = tile[tx][ty + i * 8];
}

// ---------------- GEMM: C = A[M][K] @ Bt[N][K]^T (bf16 in, fp32 acc) ----------------
// r3-exact (best measured: G1 = 67.3-71.6 us across 6 rounds). 256x128 tile,
// BK=64, 8 waves 4Mx2N, m201-style phase pair per K-tile, 3-slot LDS ring,
// counted vmcnt(6). modeC 1: fp32 out stride N. modeC 2: QKV split epilogue.
__global__ __launch_bounds__(512, 2) void gemm256(const bf16* __restrict__ A,
                                                  const bf16* __restrict__ Bt,
                                                  void* __restrict__ C,
                                                  bf16* __restrict__ Kf,
                                                  bf16* __restrict__ Vf,
                                                  int M, int N, int K,
                                                  int modeC) {
    __shared__ bf16 As[3][256 * 64];   // 3 x 32 KB
    __shared__ bf16 Bs[3][128 * 64];   // 3 x 16 KB
    const int t = threadIdx.x;
    const int m0 = blockIdx.y * 256, n0 = blockIdx.x * 128;
    const int w = t >> 6, lane = t & 63, quad = lane >> 4, l15 = lane & 15;
    const int wr = (w >> 1) * 64, wc = (w & 1) * 64;
    const int sr = t >> 3;                     // staging row within a 64-row issue
    const int sg = ((t & 7) ^ (sr & 7)) * 8;   // pre-swizzled k-segment (elements)
    const int xorL = (l15 & 7) * 8;

    // per-thread global staging bases (advance by 64 per staged tile)
    const bf16* a0 = A + (size_t)(m0 + sr) * K + sg;
    const bf16* a1 = A + (size_t)(m0 + 64 + sr) * K + sg;
    const bf16* a2 = A + (size_t)(m0 + 128 + sr) * K + sg;
    const bf16* a3 = A + (size_t)(m0 + 192 + sr) * K + sg;
    const bf16* b0 = Bt + (size_t)(n0 + sr) * K + sg;
    const bf16* b1 = Bt + (size_t)(n0 + 64 + sr) * K + sg;
    const int ldsOff = w * 512;   // wave-uniform LDS landing offset

    f32x4 acc[4][4];
    const f32x4 zero4 = {0.f, 0.f, 0.f, 0.f};
#pragma unroll
    for (int i = 0; i < 4; ++i)
#pragma unroll
        for (int j = 0; j < 4; ++j) acc[i][j] = zero4;

    const int nt = K >> 6;

    // prologue: stage tiles 0 and 1 (6 gloads each: A x4, B x2)
    gload_lds16(a0, &As[0][0 * 4096 + ldsOff]);
    gload_lds16(a1, &As[0][1 * 4096 + ldsOff]);
    gload_lds16(a2, &As[0][2 * 4096 + ldsOff]);
    gload_lds16(a3, &As[0][3 * 4096 + ldsOff]);
    gload_lds16(b0, &Bs[0][0 * 4096 + ldsOff]);
    gload_lds16(b1, &Bs[0][1 * 4096 + ldsOff]);
    if (nt > 1) {
        gload_lds16(a0 + 64, &As[1][0 * 4096 + ldsOff]);
        gload_lds16(a1 + 64, &As[1][1 * 4096 + ldsOff]);
        gload_lds16(a2 + 64, &As[1][2 * 4096 + ldsOff]);
        gload_lds16(a3 + 64, &As[1][3 * 4096 + ldsOff]);
        gload_lds16(b0 + 64, &Bs[1][0 * 4096 + ldsOff]);
        gload_lds16(b1 + 64, &Bs[1][1 * 4096 + ldsOff]);
        asm volatile("s_waitcnt vmcnt(6)" ::: "memory");
    } else {
        asm volatile("s_waitcnt vmcnt(0)" ::: "memory");
    }
    __builtin_amdgcn_sched_barrier(0);
    __builtin_amdgcn_s_barrier();
    __builtin_amdgcn_sched_barrier(0);

    int cur = 0;
    for (int tt = 0; tt < nt; ++tt) {
        const bf16* Ac = As[cur];
        const bf16* Bc = Bs[cur];
        int pf = cur + 2; if (pf >= 3) pf -= 3;      // ring slot for tile tt+2
        const bool do_pf = (tt + 2 < nt);
        const int kpf = (tt + 2) << 6;

        // ================= phase 0 (kk = 0) =================
        {
            const int colOff = (quad * 8) ^ xorL;
            bf16x8 af[4], bfv[4];
#pragma unroll
            for (int i = 0; i < 4; ++i)
                af[i] = *(const bf16x8*)(Ac + (wr + i * 16 + l15) * 64 + colOff);
#pragma unroll
            for (int j = 0; j < 4; ++j)
                bfv[j] = *(const bf16x8*)(Bc + (wc + j * 16 + l15) * 64 + colOff);
            if (do_pf) {
                gload_lds16(a0 + kpf, &As[pf][0 * 4096 + ldsOff]);
                gload_lds16(a1 + kpf, &As[pf][1 * 4096 + ldsOff]);
                gload_lds16(a2 + kpf, &As[pf][2 * 4096 + ldsOff]);
            }
            __builtin_amdgcn_sched_barrier(0);
            __builtin_amdgcn_s_barrier();
            asm volatile("s_waitcnt lgkmcnt(0)" ::: "memory");
            __builtin_amdgcn_sched_barrier(0);
            __builtin_amdgcn_s_setprio(1);
#pragma unroll
            for (int i = 0; i < 4; ++i)
#pragma unroll
                for (int j = 0; j < 4; ++j)
                    acc[i][j] = __builtin_amdgcn_mfma_f32_16x16x32_bf16(af[i], bfv[j], acc[i][j], 0, 0, 0);
            __builtin_amdgcn_s_setprio(0);
            __builtin_amdgcn_sched_barrier(0);
            __builtin_amdgcn_s_barrier();
            __builtin_amdgcn_sched_barrier(0);
        }

        // ================= phase 1 (kk = 1) =================
        {
            const int colOff = (32 + quad * 8) ^ xorL;
            bf16x8 af[4], bfv[4];
#pragma unroll
            for (int i = 0; i < 4; ++i)
                af[i] = *(const bf16x8*)(Ac + (wr + i * 16 + l15) * 64 + colOff);
#pragma unroll
            for (int j = 0; j < 4; ++j)
                bfv[j] = *(const bf16x8*)(Bc + (wc + j * 16 + l15) * 64 + colOff);
            if (do_pf) {
                gload_lds16(a3 + kpf, &As[pf][3 * 4096 + ldsOff]);
                gload_lds16(b0 + kpf, &Bs[pf][0 * 4096 + ldsOff]);
                gload_lds16(b1 + kpf, &Bs[pf][1 * 4096 + ldsOff]);
                asm volatile("s_waitcnt vmcnt(6)" ::: "memory");   // tile tt+1 retired, tt+2 in flight
            } else {
                asm volatile("s_waitcnt vmcnt(0)" ::: "memory");   // tail: drain
            }
            __builtin_amdgcn_sched_barrier(0);
            __builtin_amdgcn_s_barrier();
            asm volatile("s_waitcnt lgkmcnt(0)" ::: "memory");
            __builtin_amdgcn_sched_barrier(0);
            __builtin_amdgcn_s_setprio(1);
#pragma unroll
            for (int i = 0; i < 4; ++i)
#pragma unroll
                for (int j = 0; j < 4; ++j)
                    acc[i][j] = __builtin_amdgcn_mfma_f32_16x16x32_bf16(af[i], bfv[j], acc[i][j], 0, 0, 0);
            __builtin_amdgcn_s_setprio(0);
            __builtin_amdgcn_sched_barrier(0);
            __builtin_amdgcn_s_barrier();
            __builtin_amdgcn_sched_barrier(0);
        }
        cur = cur + 1; if (cur == 3) cur = 0;
    }

    // epilogue — C/D layout: row = quad*4 + reg, col = l15 (m89/m91 verified)
    if (modeC == 1) {
        float* Cf = (float*)C;
        for (int i = 0; i < 4; ++i)
            for (int fc = 0; fc < 4; ++fc)
                for (int r = 0; r < 4; ++r)
                    Cf[(size_t)(m0 + wr + i * 16 + quad * 4 + r) * N
                       + (n0 + wc + fc * 16 + l15)] = acc[i][fc][r];
    } else if (n0 < 1024) {
        bf16* q = (bf16*)C;
        for (int i = 0; i < 4; ++i)
            for (int fc = 0; fc < 4; ++fc)
                for (int r = 0; r < 4; ++r)
                    q[(size_t)(m0 + wr + i * 16 + quad * 4 + r) * 1024
                      + (n0 + wc + fc * 16 + l15)] = (bf16)(acc[i][fc][r] * QSCALE);
    } else if (n0 < 2048) {
        // K region -> Kf fragment layout
        for (int i = 0; i < 4; ++i) {
            int rowb = m0 + wr + i * 16 + quad * 4;
            int nb = rowb >> 11, tt = rowb & 2047;
            int kt = tt >> 6, f = (tt >> 4) & 3, l15k = tt & 15;
            for (int fc = 0; fc < 4; ++fc) {
                int col = n0 + wc + fc * 16 + l15 - 1024;
                int h = col >> 6, dk = col & 63;
                int ks = dk >> 5, qdk = (dk >> 3) & 3, j = dk & 7;
                size_t base = ((size_t)((nb * 16 + h) * 32 + kt) * 8 + ks * 4 + f) * 512 + j;
                for (int r = 0; r < 4; ++r)
                    Kf[base + (qdk * 16 + l15k + r) * 8] = (bf16)acc[i][fc][r];
            }
        }
    } else {
        // V region -> Vf fragment layout (packed ushort4)
        for (int i = 0; i < 4; ++i) {
            int rowb = m0 + wr + i * 16 + quad * 4;
            int nb = rowb >> 11, tt = rowb & 2047;
            int kt = tt >> 6, ks = (tt >> 5) & 1, qdv = (tt >> 3) & 3, j0 = tt & 7;
            for (int fc = 0; fc < 4; ++fc) {
                int col = n0 + wc + fc * 16 + l15 - 2048;
                int h = col >> 6, dl = col & 63;
                int fv = dl >> 4, l15v = dl & 15;
                union { ushort4 u; bf16 hh[4]; } pk;
                for (int r = 0; r < 4; ++r) pk.hh[r] = (bf16)acc[i][fc][r];
                *(ushort4*)(Vf + ((size_t)((nb * 16 + h) * 32 + kt) * 8 + ks * 4 + fv) * 512
                            + (qdv * 16 + l15v) * 8 + j0) = pk.u;
            }
        }
    }
}

// ---------------- fused causal attention, S^T form, no online max ----------------
// r10: r8 structure (block = head x 128-row q-tile, 4 waves, K/V staged once to
// LDS) + DEEP PIPELINE: 3-slot K/V ring, tile kt+2 issued before compute of kt,
// counted s_waitcnt vmcnt(4) at the tile boundary (tile kt+1 retired, kt+2 in
// flight a full tile) — replaces r8's __syncthreads which drained vmcnt(0)
// every tile and put the full L3/HBM latency on the critical path. Raw
// s_barrier; slot-reuse safety identical to the GEMM ring proof. Compute math
// bitwise-identical to r8. LDS 66 KB -> 2 blocks/CU.
#define LDP 72
__global__ __launch_bounds__(256, 2) void attn_fused(const bf16* __restrict__ q,
                                                     const bf16* __restrict__ Kf,
                                                     const bf16* __restrict__ Vf,
                                                     bf16* __restrict__ attn_out) {
    __shared__ bf16 Ks[3][4096];        // 3 x 8 KB K tile (fragment layout)
    __shared__ bf16 Vs[3][4096];        // 3 x 8 KB V tile
    __shared__ bf16 Pl[4 * 32 * LDP];   // per-wave private 32x64 P strip

    const int b = blockIdx.x;
    const int head = b & 63;
    const int qt = 15 - (b >> 6);       // descending: longest blocks first
    const int n = head >> 4, h = head & 15;
    const int t = threadIdx.x;
    const int w = t >> 6, lane = t & 63, qd = lane >> 4, l15 = lane & 15;
    const int q0w = qt * 128 + w * 32;  // this wave's 32 q-rows
    const size_t rowBase = (size_t)n * T_S;
    const bf16* KfH = Kf + (size_t)head * 32 * 4096;
    const bf16* VfH = Vf + (size_t)head * 32 * 4096;
    bf16* Plw = Pl + w * 32 * LDP;
    const int sc = w * 2;               // staging chunk base (2 chunks of 512 elem per wave)

    // persistent Q b-frags (pre-scaled by QSCALE): [qh][ks]
    bf16x8 bQ[2][2];
#pragma unroll
    for (int qh = 0; qh < 2; ++qh)
#pragma unroll
        for (int ks = 0; ks < 2; ++ks)
            bQ[qh][ks] = *(const bf16x8*)(q + (rowBase + q0w + qh * 16 + l15) * 1024
                                          + h * 64 + ks * 32 + qd * 8);

    float l_lane[2] = {0.f, 0.f};
    f32x4 oacc[2][4];
    const f32x4 zero4 = {0.f, 0.f, 0.f, 0.f};
#pragma unroll
    for (int qh = 0; qh < 2; ++qh)
#pragma unroll
        for (int fd = 0; fd < 4; ++fd) oacc[qh][fd] = zero4;

    const int ktmax_w = (q0w + 31) >> 6;        // this wave's causal compute limit
    const int ktmax_b = (qt * 128 + 127) >> 6;  // block stage limit = 2*qt+1

    // prologue: stage tile 0 (slot 0) and tile 1 (slot 1); counted wait
    gload_lds16(KfH + (sc + 0) * 512 + lane * 8, &Ks[0][(sc + 0) * 512]);
    gload_lds16(KfH + (sc + 1) * 512 + lane * 8, &Ks[0][(sc + 1) * 512]);
    gload_lds16(VfH + (sc + 0) * 512 + lane * 8, &Vs[0][(sc + 0) * 512]);
    gload_lds16(VfH + (sc + 1) * 512 + lane * 8, &Vs[0][(sc + 1) * 512]);
    if (ktmax_b >= 1) {
        const bf16* K1 = KfH + 4096;
        const bf16* V1 = VfH + 4096;
        gload_lds16(K1 + (sc + 0) * 512 + lane * 8, &Ks[1][(sc + 0) * 512]);
        gload_lds16(K1 + (sc + 1) * 512 + lane * 8, &Ks[1][(sc + 1) * 512]);
        gload_lds16(V1 + (sc + 0) * 512 + lane * 8, &Vs[1][(sc + 0) * 512]);
        gload_lds16(V1 + (sc + 1) * 512 + lane * 8, &Vs[1][(sc + 1) * 512]);
        asm volatile("s_waitcnt vmcnt(4)" ::: "memory");   // tile 0 landed, tile 1 in flight
    } else {
        asm volatile("s_waitcnt vmcnt(0)" ::: "memory");
    }
    __builtin_amdgcn_sched_barrier(0);
    __builtin_amdgcn_s_barrier();
    __builtin_amdgcn_sched_barrier(0);

    int cur = 0;
    for (int kt = 0; kt <= ktmax_b; ++kt) {
        // issue tile kt+2 into ring slot pf (= slot of tile kt-1, consumed and
        // barrier-released last iteration) BEFORE compute — in flight during it
        if (kt + 2 <= ktmax_b) {
            int pf = cur + 2; if (pf >= 3) pf -= 3;
            const bf16* Kn = KfH + (size_t)(kt + 2) * 4096;
            const bf16* Vn = VfH + (size_t)(kt + 2) * 4096;
            gload_lds16(Kn + (sc + 0) * 512 + lane * 8, &Ks[pf][(sc + 0) * 512]);
            gload_lds16(Kn + (sc + 1) * 512 + lane * 8, &Ks[pf][(sc + 1) * 512]);
            gload_lds16(Vn + (sc + 0) * 512 + lane * 8, &Vs[pf][(sc + 0) * 512]);
            gload_lds16(Vn + (sc + 1) * 512 + lane * 8, &Vs[pf][(sc + 1) * 512]);
        }

        if (kt <= ktmax_w) {   // wave-uniform predicate; issue/wait/barrier outside
            const int k0r = kt * 64;

            // K frags from LDS (identical values/offsets as r8)
            bf16x8 aK[2][4];
#pragma unroll
            for (int fr = 0; fr < 8; ++fr)
                aK[fr >> 2][fr & 3] = *(const bf16x8*)(&Ks[cur][fr * 512 + lane * 8]);

            // S^T[kv][q] = K @ Q^T
            f32x4 sacc[2][4];
#pragma unroll
            for (int qh = 0; qh < 2; ++qh)
#pragma unroll
                for (int fc = 0; fc < 4; ++fc) sacc[qh][fc] = zero4;
#pragma unroll
            for (int ks = 0; ks < 2; ++ks)
#pragma unroll
                for (int fc = 0; fc < 4; ++fc) {
                    sacc[0][fc] = __builtin_amdgcn_mfma_f32_16x16x32_bf16(aK[ks][fc], bQ[0][ks], sacc[0][fc], 0, 0, 0);
                    sacc[1][fc] = __builtin_amdgcn_mfma_f32_16x16x32_bf16(aK[ks][fc], bQ[1][ks], sacc[1][fc], 0, 0, 0);
                }

            // causal mask (diagonal tiles only)
            if (k0r + 63 > q0w) {
#pragma unroll
                for (int qh = 0; qh < 2; ++qh) {
                    const int qq = q0w + qh * 16 + l15;
#pragma unroll
                    for (int fc = 0; fc < 4; ++fc)
#pragma unroll
                        for (int rr = 0; rr < 4; ++rr)
                            if (k0r + fc * 16 + qd * 4 + rr > qq) sacc[qh][fc][rr] = NEG_BIG;
                }
            }

            // P = exp2(S) — native v_exp_f32; per-lane l accumulation
#pragma unroll
            for (int qh = 0; qh < 2; ++qh) {
                float rs = 0.f;
#pragma unroll
                for (int fc = 0; fc < 4; ++fc) {
                    union { ushort4 u; bf16 hh[4]; } pk;
#pragma unroll
                    for (int rr = 0; rr < 4; ++rr) {
                        float p = EXP2(sacc[qh][fc][rr]);
                        rs += p;
                        pk.hh[rr] = (bf16)p;
                    }
                    *(ushort4*)(Plw + (qh * 16 + l15) * LDP + fc * 16 + qd * 4) = pk.u;
                }
                l_lane[qh] += rs;
            }

            // V frags from LDS, then O^T += Vt @ P^T
            bf16x8 aV[2][4];
#pragma unroll
            for (int fr = 0; fr < 8; ++fr)
                aV[fr >> 2][fr & 3] = *(const bf16x8*)(&Vs[cur][fr * 512 + lane * 8]);
#pragma unroll
            for (int ks = 0; ks < 2; ++ks) {
                bf16x8 bP0 = *(const bf16x8*)(Plw + l15 * LDP + ks * 32 + qd * 8);
                bf16x8 bP1 = *(const bf16x8*)(Plw + (16 + l15) * LDP + ks * 32 + qd * 8);
#pragma unroll
                for (int fd = 0; fd < 4; ++fd) {
                    oacc[0][fd] = __builtin_amdgcn_mfma_f32_16x16x32_bf16(aV[ks][fd], bP0, oacc[0][fd], 0, 0, 0);
                    oacc[1][fd] = __builtin_amdgcn_mfma_f32_16x16x32_bf16(aV[ks][fd], bP1, oacc[1][fd], 0, 0, 0);
                }
            }
        }

        // tile boundary: publish tile kt+1 (counted — tile kt+2 stays in flight),
        // and release slot cur for reuse next iteration
        if (kt < ktmax_b) {
            if (kt + 2 <= ktmax_b) {
                asm volatile("s_waitcnt vmcnt(4)" ::: "memory");
            } else {
                asm volatile("s_waitcnt vmcnt(0)" ::: "memory");
            }
            __builtin_amdgcn_sched_barrier(0);
            __builtin_amdgcn_s_barrier();
            __builtin_amdgcn_sched_barrier(0);
        }
        cur = cur + 1; if (cur == 3) cur = 0;
    }

    // epilogue: reduce l across the 4 kv-quads, scale, store
#pragma unroll
    for (int qh = 0; qh < 2; ++qh) {
        float l = l_lane[qh];
        l += __shfl_xor(l, 16, 64);
        l += __shfl_xor(l, 32, 64);
        float inv = 1.f / l;
#pragma unroll
        for (int fd = 0; fd < 4; ++fd) {
            union { ushort4 u; bf16 hh[4]; } pk;
#pragma unroll
            for (int rr = 0; rr < 4; ++rr) pk.hh[rr] = (bf16)(oacc[qh][fd][rr] * inv);
            *(ushort4*)(attn_out + (rowBase + q0w + qh * 16 + l15) * D_M
                        + h * D_K + fd * 16 + qd * 4) = pk.u;
        }
    }
}

extern "C" void kernel_launch(void* const* d_in, const int* in_sizes, int n_in,
                              void* d_out, int out_size, void* d_ws, size_t ws_size,
                              hipStream_t stream) {
    const void* z    = d_in[0];   // [4,2048,1024]  fp32 (or bf16)
    const void* Wqkv = d_in[1];   // [1024,3072]
    const void* Wout = d_in[2];   // [1024,1024]

    char* ws = (char*)d_ws;
    bf16* q     = (bf16*)(ws + 256);                           // 16,777,216 B  [8192][1024]
    bf16* attn  = (bf16*)(ws + 256 + 16777216);                // 16,777,216 B
    bf16* zb    = attn;  // aliased: zb dead before attn is written
    bf16* WqkvT = (bf16*)(ws + 256 + 2 * 16777216);            //  6,291,456 B
    bf16* WoutT = (bf16*)(ws + 256 + 2 * 16777216 + 6291456);  //  2,097,152 B

    // Kf/Vf fragment-packed K/V live in d_out (33,554,432 B exact fit) —
    // written by GEMM1's epilogue, read by attn, then fully overwritten by GEMM2.
    bf16* Kf = (bf16*)d_out;
    bf16* Vf = Kf + 8388608;

    // fused prologue: z->bf16 + both weight transposes (per-block dtype probe)
    prep<<<dim3(8192), 256, 0, stream>>>(z, zb, Wqkv, WqkvT, Wout, WoutT);

    // qkv = zb @ Wqkv : q(*QSCALE) -> q, k -> Kf frags, v -> Vf frags
    gemm256<<<dim3(D3 / 128, (N_B * T_S) / 256), 512, 0, stream>>>(
        zb, WqkvT, q, Kf, Vf, N_B * T_S, D3, D_M, 2);

    attn_fused<<<dim3(64 * 16), 256, 0, stream>>>(q, Kf, Vf, attn);

    // out = attn @ Wout : [8192 x 1024] fp32 out (overwrites Kf/Vf scratch)
    gemm256<<<dim3(D_M / 128, (N_B * T_S) / 256), 512, 0, stream>>>(
        attn, WoutT, d_out, Kf, Vf, N_B * T_S, D_M, D_M, 1);
}

// Round 11
// 227.505 us; speedup vs baseline: 1.0241x; 1.0240x over previous
//
#include <hip/hip_runtime.h>
#include <hip/hip_bf16.h>

typedef __bf16 bf16;
typedef __bf16 bf16x8 __attribute__((ext_vector_type(8)));
typedef float f32x4 __attribute__((ext_vector_type(4)));

#define N_B 4
#define T_S 2048
#define D_M 1024
#define H_N 16
#define D_K 64
#define D3 3072
#define NEG_BIG (-1e30f)
#define QSCALE 0.18033688011112042f  /* 0.125 * log2(e) */

#if __has_builtin(__builtin_amdgcn_exp2f)
#define EXP2(x) __builtin_amdgcn_exp2f(x)
#else
#define EXP2(x) exp2f(x)
#endif

__device__ __forceinline__ void gload_lds16(const bf16* g, bf16* l) {
    __builtin_amdgcn_global_load_lds((const __attribute__((address_space(1))) void*)g,
                                     (__attribute__((address_space(3))) void*)l, 16, 0, 0);
}

// Probe: true => data is fp32 (see r0 notes).
__device__ __forceinline__ bool probe_fp32(const void* p) {
    const unsigned int* w = (const unsigned int*)p;
    int weird = 0;
#pragma unroll
    for (int i = 0; i < 16; ++i) {
        unsigned int v = w[i];
        unsigned int e = (v >> 7) & 0xFFu;
        if ((v & 0xFFFFu) != 0u && (e < 100u || e > 140u)) weird++;
    }
    return weird >= 4;
}

// ---------------- fused prologue: convert z + transpose both weights ----------------
__global__ __launch_bounds__(256) void prep(const void* __restrict__ z, bf16* __restrict__ zb,
                                            const void* __restrict__ Wqkv, bf16* __restrict__ WqkvT,
                                            const void* __restrict__ Wout, bf16* __restrict__ WoutT) {
    __shared__ bf16 tile[32][33];
    const int b = blockIdx.x;
    const int t = threadIdx.x;

    if (b < 4096) {
        const int i = (b * 256 + t) * 8;
        if (probe_fp32(z)) {
            const float* zf = (const float*)z;
            float4 u0 = *(const float4*)(zf + i);
            float4 u1 = *(const float4*)(zf + i + 4);
            union { uint4 q; bf16 h[8]; } pk;
            pk.h[0] = (bf16)u0.x; pk.h[1] = (bf16)u0.y;
            pk.h[2] = (bf16)u0.z; pk.h[3] = (bf16)u0.w;
            pk.h[4] = (bf16)u1.x; pk.h[5] = (bf16)u1.y;
            pk.h[6] = (bf16)u1.z; pk.h[7] = (bf16)u1.w;
            *(uint4*)(zb + i) = pk.q;
        } else {
            *(uint4*)(zb + i) = ((const uint4*)z)[b * 256 + t];
        }
        return;
    }

    const void* in; bf16* out; int R, C, c0, r0;
    if (b < 7168) {
        int idx = b - 4096;
        in = Wqkv; out = WqkvT; R = 1024; C = 3072;
        c0 = (idx % 96) * 32; r0 = (idx / 96) * 32;
    } else {
        int idx = b - 7168;
        in = Wout; out = WoutT; R = 1024; C = 1024;
        c0 = (idx & 31) * 32; r0 = (idx >> 5) * 32;
    }
    const int tx = t & 31, ty = t >> 5;
    if (probe_fp32(in)) {
        const float* inf_ = (const float*)in;
        for (int i = 0; i < 4; ++i)
            tile[ty + i * 8][tx] = (bf16)inf_[(size_t)(r0 + ty + i * 8) * C + c0 + tx];
    } else {
        const bf16* inb = (const bf16*)in;
        for (int i = 0; i < 4; ++i)
            tile[ty + i * 8][tx] = inb[(size_t)(r0 + ty + i * 8) * C + c0 + tx];
    }
    __syncthreads();
    for (int i = 0; i < 4; ++i)
        out[(size_t)(c0 + ty + i * 8) * R + r0 + tx] = tile[tx][ty + i * 8];
}

// ---------------- GEMM: C = A[M][K] @ Bt[N][K]^T (bf16 in, fp32 acc) ----------------
// r11: r3's proven ring schedule with BK 64 -> 32 for 2-BLOCKS/CU OCCUPANCY.
// 256x128 tile, BK=32, 8 waves 4Mx2N, per-wave 64x64 (4x4 frags), one
// 16-MFMA phase per K-tile. LDS = 3-slot ring x (16KB A + 8KB B) = 72 KB ->
// 2 blocks/CU (16 waves/CU): a co-resident block's MFMA fills this block's
// barrier/vmcnt stalls (m97 mechanism — the lever no prior round pulled).
// Counted vmcnt(3): tile tt+2's 3 loads issued at tile tt, wait retires tt+1,
// never drains to 0 except the last tile (same accounting proof as r3).
// K=32 MFMA sub-steps execute in r3's exact kk order -> bitwise-identical acc.
// Swizzle for 32-elem rows: seg (col>>3) ^ ((row>>1)&3) — <=2-way bank alias
// (free, m136); staged via pre-swizzled GLOBAL source (both-sides rule).
// modeC 1: fp32 out stride N. modeC 2: QKV split epilogue (q/Kf/Vf).
__global__ __launch_bounds__(512, 4) void gemm32(const bf16* __restrict__ A,
                                                 const bf16* __restrict__ Bt,
                                                 void* __restrict__ C,
                                                 bf16* __restrict__ Kf,
                                                 bf16* __restrict__ Vf,
                                                 int M, int N, int K,
                                                 int modeC) {
    __shared__ bf16 As[3][256 * 32];   // 3 x 16 KB (two 128-row chunks each)
    __shared__ bf16 Bs[3][128 * 32];   // 3 x  8 KB
    const int t = threadIdx.x;
    const int m0 = blockIdx.y * 256, n0 = blockIdx.x * 128;
    const int w = t >> 6, lane = t & 63, quad = lane >> 4, l15 = lane & 15;
    const int wr = (w >> 1) * 64, wc = (w & 1) * 64;

    // staging map: thread t covers row (t>>2) of a 128-row chunk, k-seg (t&3),
    // source pre-swizzled so LDS (row, s) holds global (row, s ^ ((row>>1)&3))
    const int asr = t >> 2;
    const int aseg = ((t & 3) ^ ((asr >> 1) & 3)) * 8;
    const bf16* aA0 = A + (size_t)(m0 + asr) * K + aseg;         // A chunk 0
    const bf16* aA1 = A + (size_t)(m0 + 128 + asr) * K + aseg;   // A chunk 1
    const bf16* aB0 = Bt + (size_t)(n0 + asr) * K + aseg;        // B (128 rows)
    const int ldsOff = w * 512;   // wave-uniform LDS landing offset (elements)

    // read swizzle: lane (quad,l15) reads logical k-seg quad of row base+l15;
    // stored position = quad ^ ((l15>>1)&3)  (base rows are multiples of 16)
    const int colOff = ((quad ^ ((l15 >> 1) & 3)) * 8);

    f32x4 acc[4][4];
    const f32x4 zero4 = {0.f, 0.f, 0.f, 0.f};
#pragma unroll
    for (int i = 0; i < 4; ++i)
#pragma unroll
        for (int j = 0; j < 4; ++j) acc[i][j] = zero4;

    const int nt = K >> 5;

    // prologue: stage tiles 0 (slot 0) and 1 (slot 1); 3 gloads each
    gload_lds16(aA0, &As[0][0 * 4096 + ldsOff]);
    gload_lds16(aA1, &As[0][1 * 4096 + ldsOff]);
    gload_lds16(aB0, &Bs[0][ldsOff]);
    if (nt > 1) {
        gload_lds16(aA0 + 32, &As[1][0 * 4096 + ldsOff]);
        gload_lds16(aA1 + 32, &As[1][1 * 4096 + ldsOff]);
        gload_lds16(aB0 + 32, &Bs[1][ldsOff]);
        asm volatile("s_waitcnt vmcnt(3)" ::: "memory");   // tile 0 landed, tile 1 in flight
    } else {
        asm volatile("s_waitcnt vmcnt(0)" ::: "memory");
    }
    __builtin_amdgcn_sched_barrier(0);
    __builtin_amdgcn_s_barrier();
    __builtin_amdgcn_sched_barrier(0);

    int cur = 0;
    for (int tt = 0; tt < nt; ++tt) {
        const bf16* Ac = As[cur];
        const bf16* Bc = Bs[cur];
        int pf = cur + 2; if (pf >= 3) pf -= 3;      // ring slot for tile tt+2

        // ds_reads of tile tt (published at previous boundary)
        bf16x8 af[4], bfv[4];
#pragma unroll
        for (int i = 0; i < 4; ++i)
            af[i] = *(const bf16x8*)(Ac + (wr + i * 16 + l15) * 32 + colOff);
#pragma unroll
        for (int j = 0; j < 4; ++j)
            bfv[j] = *(const bf16x8*)(Bc + (wc + j * 16 + l15) * 32 + colOff);

        // stage tile tt+2 into slot pf (slot of tile tt-1 — its readers drained
        // before last iteration's closing barrier), then counted wait
        if (tt + 2 < nt) {
            const int kpf = (tt + 2) << 5;
            gload_lds16(aA0 + kpf, &As[pf][0 * 4096 + ldsOff]);
            gload_lds16(aA1 + kpf, &As[pf][1 * 4096 + ldsOff]);
            gload_lds16(aB0 + kpf, &Bs[pf][ldsOff]);
        }
        if (tt == nt - 1) {
            asm volatile("s_waitcnt vmcnt(0)" ::: "memory");   // tail drain
        } else {
            asm volatile("s_waitcnt vmcnt(3)" ::: "memory");   // tt+1 retired, tt+2 in flight
        }
        __builtin_amdgcn_sched_barrier(0);
        __builtin_amdgcn_s_barrier();
        asm volatile("s_waitcnt lgkmcnt(0)" ::: "memory");
        __builtin_amdgcn_sched_barrier(0);
        __builtin_amdgcn_s_setprio(1);
#pragma unroll
        for (int i = 0; i < 4; ++i)
#pragma unroll
            for (int j = 0; j < 4; ++j)
                acc[i][j] = __builtin_amdgcn_mfma_f32_16x16x32_bf16(af[i], bfv[j], acc[i][j], 0, 0, 0);
        __builtin_amdgcn_s_setprio(0);
        __builtin_amdgcn_sched_barrier(0);
        __builtin_amdgcn_s_barrier();
        __builtin_amdgcn_sched_barrier(0);

        cur = cur + 1; if (cur == 3) cur = 0;
    }

    // epilogue — C/D layout: row = quad*4 + reg, col = l15 (m89/m91 verified)
    if (modeC == 1) {
        float* Cf = (float*)C;
        for (int i = 0; i < 4; ++i)
            for (int fc = 0; fc < 4; ++fc)
                for (int r = 0; r < 4; ++r)
                    Cf[(size_t)(m0 + wr + i * 16 + quad * 4 + r) * N
                       + (n0 + wc + fc * 16 + l15)] = acc[i][fc][r];
    } else if (n0 < 1024) {
        bf16* q = (bf16*)C;
        for (int i = 0; i < 4; ++i)
            for (int fc = 0; fc < 4; ++fc)
                for (int r = 0; r < 4; ++r)
                    q[(size_t)(m0 + wr + i * 16 + quad * 4 + r) * 1024
                      + (n0 + wc + fc * 16 + l15)] = (bf16)(acc[i][fc][r] * QSCALE);
    } else if (n0 < 2048) {
        // K region -> Kf fragment layout
        for (int i = 0; i < 4; ++i) {
            int rowb = m0 + wr + i * 16 + quad * 4;
            int nb = rowb >> 11, tt = rowb & 2047;
            int kt = tt >> 6, f = (tt >> 4) & 3, l15k = tt & 15;
            for (int fc = 0; fc < 4; ++fc) {
                int col = n0 + wc + fc * 16 + l15 - 1024;
                int h = col >> 6, dk = col & 63;
                int ks = dk >> 5, qdk = (dk >> 3) & 3, j = dk & 7;
                size_t base = ((size_t)((nb * 16 + h) * 32 + kt) * 8 + ks * 4 + f) * 512 + j;
                for (int r = 0; r < 4; ++r)
                    Kf[base + (qdk * 16 + l15k + r) * 8] = (bf16)acc[i][fc][r];
            }
        }
    } else {
        // V region -> Vf fragment layout (packed ushort4)
        for (int i = 0; i < 4; ++i) {
            int rowb = m0 + wr + i * 16 + quad * 4;
            int nb = rowb >> 11, tt = rowb & 2047;
            int kt = tt >> 6, ks = (tt >> 5) & 1, qdv = (tt >> 3) & 3, j0 = tt & 7;
            for (int fc = 0; fc < 4; ++fc) {
                int col = n0 + wc + fc * 16 + l15 - 2048;
                int h = col >> 6, dl = col & 63;
                int fv = dl >> 4, l15v = dl & 15;
                union { ushort4 u; bf16 hh[4]; } pk;
                for (int r = 0; r < 4; ++r) pk.hh[r] = (bf16)acc[i][fc][r];
                *(ushort4*)(Vf + ((size_t)((nb * 16 + h) * 32 + kt) * 8 + ks * 4 + fv) * 512
                            + (qdv * 16 + l15v) * 8 + j0) = pk.u;
            }
        }
    }
}

// ---------------- fused causal attention, S^T form, no online max ----------------
// r8-exact (best measured total: 225.9 us). Block = (head, 128-row q-tile),
// 4 waves lockstep; K/V tile staged ONCE to LDS (global_load_lds, double
// buffer, __syncthreads publishes). Cuts K/V global traffic 4x vs per-wave
// streaming. Per-q-row math/MFMA order identical across rounds.
#define LDP 72
__global__ __launch_bounds__(256, 2) void attn_fused(const bf16* __restrict__ q,
                                                     const bf16* __restrict__ Kf,
                                                     const bf16* __restrict__ Vf,
                                                     bf16* __restrict__ attn_out) {
    __shared__ bf16 Ks[2][4096];        // 2 x 8 KB K tile (fragment layout)
    __shared__ bf16 Vs[2][4096];        // 2 x 8 KB V tile
    __shared__ bf16 Pl[4 * 32 * LDP];   // per-wave private 32x64 P strip

    const int b = blockIdx.x;
    const int head = b & 63;
    const int qt = 15 - (b >> 6);       // descending: longest blocks first
    const int n = head >> 4, h = head & 15;
    const int t = threadIdx.x;
    const int w = t >> 6, lane = t & 63, qd = lane >> 4, l15 = lane & 15;
    const int q0w = qt * 128 + w * 32;  // this wave's 32 q-rows
    const size_t rowBase = (size_t)n * T_S;
    const bf16* KfH = Kf + (size_t)head * 32 * 4096;
    const bf16* VfH = Vf + (size_t)head * 32 * 4096;
    bf16* Plw = Pl + w * 32 * LDP;
    const int sc = w * 2;               // staging chunk base (2 chunks of 512 elem per wave)

    // persistent Q b-frags (pre-scaled by QSCALE): [qh][ks]
    bf16x8 bQ[2][2];
#pragma unroll
    for (int qh = 0; qh < 2; ++qh)
#pragma unroll
        for (int ks = 0; ks < 2; ++ks)
            bQ[qh][ks] = *(const bf16x8*)(q + (rowBase + q0w + qh * 16 + l15) * 1024
                                          + h * 64 + ks * 32 + qd * 8);

    float l_lane[2] = {0.f, 0.f};
    f32x4 oacc[2][4];
    const f32x4 zero4 = {0.f, 0.f, 0.f, 0.f};
#pragma unroll
    for (int qh = 0; qh < 2; ++qh)
#pragma unroll
        for (int fd = 0; fd < 4; ++fd) oacc[qh][fd] = zero4;

    const int ktmax_w = (q0w + 31) >> 6;        // this wave's causal compute limit
    const int ktmax_b = (qt * 128 + 127) >> 6;  // block stage limit = 2*qt+1

    // stage tile 0 into buffer 0 (16 wave-issues across block: 4 per wave)
    gload_lds16(KfH + (sc + 0) * 512 + lane * 8, &Ks[0][(sc + 0) * 512]);
    gload_lds16(KfH + (sc + 1) * 512 + lane * 8, &Ks[0][(sc + 1) * 512]);
    gload_lds16(VfH + (sc + 0) * 512 + lane * 8, &Vs[0][(sc + 0) * 512]);
    gload_lds16(VfH + (sc + 1) * 512 + lane * 8, &Vs[0][(sc + 1) * 512]);
    __syncthreads();   // drains vmcnt -> tile 0 published

    int cur = 0;
    for (int kt = 0; kt <= ktmax_b; ++kt) {
        // prefetch tile kt+1 into the other buffer (drained by end-of-iter barrier)
        if (kt + 1 <= ktmax_b) {
            const bf16* Kn = KfH + (size_t)(kt + 1) * 4096;
            const bf16* Vn = VfH + (size_t)(kt + 1) * 4096;
            gload_lds16(Kn + (sc + 0) * 512 + lane * 8, &Ks[cur ^ 1][(sc + 0) * 512]);
            gload_lds16(Kn + (sc + 1) * 512 + lane * 8, &Ks[cur ^ 1][(sc + 1) * 512]);
            gload_lds16(Vn + (sc + 0) * 512 + lane * 8, &Vs[cur ^ 1][(sc + 0) * 512]);
            gload_lds16(Vn + (sc + 1) * 512 + lane * 8, &Vs[cur ^ 1][(sc + 1) * 512]);
        }

        if (kt <= ktmax_w) {   // wave-uniform: tiles beyond are fully masked
            const int k0r = kt * 64;

            // K frags from LDS
            bf16x8 aK[2][4];
#pragma unroll
            for (int fr = 0; fr < 8; ++fr)
                aK[fr >> 2][fr & 3] = *(const bf16x8*)(&Ks[cur][fr * 512 + lane * 8]);

            // S^T[kv][q] = K @ Q^T
            f32x4 sacc[2][4];
#pragma unroll
            for (int qh = 0; qh < 2; ++qh)
#pragma unroll
                for (int fc = 0; fc < 4; ++fc) sacc[qh][fc] = zero4;
#pragma unroll
            for (int ks = 0; ks < 2; ++ks)
#pragma unroll
                for (int fc = 0; fc < 4; ++fc) {
                    sacc[0][fc] = __builtin_amdgcn_mfma_f32_16x16x32_bf16(aK[ks][fc], bQ[0][ks], sacc[0][fc], 0, 0, 0);
                    sacc[1][fc] = __builtin_amdgcn_mfma_f32_16x16x32_bf16(aK[ks][fc], bQ[1][ks], sacc[1][fc], 0, 0, 0);
                }

            // causal mask (diagonal tiles only)
            if (k0r + 63 > q0w) {
#pragma unroll
                for (int qh = 0; qh < 2; ++qh) {
                    const int qq = q0w + qh * 16 + l15;
#pragma unroll
                    for (int fc = 0; fc < 4; ++fc)
#pragma unroll
                        for (int rr = 0; rr < 4; ++rr)
                            if (k0r + fc * 16 + qd * 4 + rr > qq) sacc[qh][fc][rr] = NEG_BIG;
                }
            }

            // P = exp2(S) — native v_exp_f32; per-lane l accumulation
#pragma unroll
            for (int qh = 0; qh < 2; ++qh) {
                float rs = 0.f;
#pragma unroll
                for (int fc = 0; fc < 4; ++fc) {
                    union { ushort4 u; bf16 hh[4]; } pk;
#pragma unroll
                    for (int rr = 0; rr < 4; ++rr) {
                        float p = EXP2(sacc[qh][fc][rr]);
                        rs += p;
                        pk.hh[rr] = (bf16)p;
                    }
                    *(ushort4*)(Plw + (qh * 16 + l15) * LDP + fc * 16 + qd * 4) = pk.u;
                }
                l_lane[qh] += rs;
            }

            // V frags from LDS, then O^T += Vt @ P^T
            bf16x8 aV[2][4];
#pragma unroll
            for (int fr = 0; fr < 8; ++fr)
                aV[fr >> 2][fr & 3] = *(const bf16x8*)(&Vs[cur][fr * 512 + lane * 8]);
#pragma unroll
            for (int ks = 0; ks < 2; ++ks) {
                bf16x8 bP0 = *(const bf16x8*)(Plw + l15 * LDP + ks * 32 + qd * 8);
                bf16x8 bP1 = *(const bf16x8*)(Plw + (16 + l15) * LDP + ks * 32 + qd * 8);
#pragma unroll
                for (int fd = 0; fd < 4; ++fd) {
                    oacc[0][fd] = __builtin_amdgcn_mfma_f32_16x16x32_bf16(aV[ks][fd], bP0, oacc[0][fd], 0, 0, 0);
                    oacc[1][fd] = __builtin_amdgcn_mfma_f32_16x16x32_bf16(aV[ks][fd], bP1, oacc[1][fd], 0, 0, 0);
                }
            }
        }

        __syncthreads();   // drains staging vmcnt + all waves' LDS reads of buf cur
        cur ^= 1;
    }

    // epilogue: reduce l across the 4 kv-quads, scale, store
#pragma unroll
    for (int qh = 0; qh < 2; ++qh) {
        float l = l_lane[qh];
        l += __shfl_xor(l, 16, 64);
        l += __shfl_xor(l, 32, 64);
        float inv = 1.f / l;
#pragma unroll
        for (int fd = 0; fd < 4; ++fd) {
            union { ushort4 u; bf16 hh[4]; } pk;
#pragma unroll
            for (int rr = 0; rr < 4; ++rr) pk.hh[rr] = (bf16)(oacc[qh][fd][rr] * inv);
            *(ushort4*)(attn_out + (rowBase + q0w + qh * 16 + l15) * D_M
                        + h * D_K + fd * 16 + qd * 4) = pk.u;
        }
    }
}

extern "C" void kernel_launch(void* const* d_in, const int* in_sizes, int n_in,
                              void* d_out, int out_size, void* d_ws, size_t ws_size,
                              hipStream_t stream) {
    const void* z    = d_in[0];   // [4,2048,1024]  fp32 (or bf16)
    const void* Wqkv = d_in[1];   // [1024,3072]
    const void* Wout = d_in[2];   // [1024,1024]

    char* ws = (char*)d_ws;
    bf16* q     = (bf16*)(ws + 256);                           // 16,777,216 B  [8192][1024]
    bf16* attn  = (bf16*)(ws + 256 + 16777216);                // 16,777,216 B
    bf16* zb    = attn;  // aliased: zb dead before attn is written
    bf16* WqkvT = (bf16*)(ws + 256 + 2 * 16777216);            //  6,291,456 B
    bf16* WoutT = (bf16*)(ws + 256 + 2 * 16777216 + 6291456);  //  2,097,152 B

    // Kf/Vf fragment-packed K/V live in d_out (33,554,432 B exact fit) —
    // written by GEMM1's epilogue, read by attn, then fully overwritten by GEMM2.
    bf16* Kf = (bf16*)d_out;
    bf16* Vf = Kf + 8388608;

    // fused prologue: z->bf16 + both weight transposes (per-block dtype probe)
    prep<<<dim3(8192), 256, 0, stream>>>(z, zb, Wqkv, WqkvT, Wout, WoutT);

    // qkv = zb @ Wqkv : q(*QSCALE) -> q, k -> Kf frags, v -> Vf frags
    gemm32<<<dim3(D3 / 128, (N_B * T_S) / 256), 512, 0, stream>>>(
        zb, WqkvT, q, Kf, Vf, N_B * T_S, D3, D_M, 2);

    attn_fused<<<dim3(64 * 16), 256, 0, stream>>>(q, Kf, Vf, attn);

    // out = attn @ Wout : [8192 x 1024] fp32 out (overwrites Kf/Vf scratch)
    gemm32<<<dim3(D_M / 128, (N_B * T_S) / 256), 512, 0, stream>>>(
        attn, WoutT, d_out, Kf, Vf, N_B * T_S, D_M, D_M, 1);
}